// Round 1
// baseline (307.635 us; speedup 1.0000x reference)
//
#include <hip/hip_runtime.h>

typedef __attribute__((ext_vector_type(8))) short short8;
typedef __attribute__((ext_vector_type(4))) short short4v;
typedef __attribute__((ext_vector_type(4))) float float4v;

#define DEV static __device__ __forceinline__

DEV float b2f(unsigned short u) { return __uint_as_float(((unsigned)u) << 16); }
DEV unsigned short f2b(float f) {
  unsigned u = __float_as_uint(f);
  return (unsigned short)((u + 0x7FFFu + ((u >> 16) & 1u)) >> 16);
}

// ws layout (2-byte units):
// [0, 49152)      qkv_w bf16  [384][128]   (out_col, k) k-contiguous
// [49152, 65536)  proj_w bf16 [128][128]
// [65536, 81920)  biasT bf16  [4][64][64]  (head, key j, row i)
__global__ void prep_kernel(const float* __restrict__ qkvw, const float* __restrict__ projw,
                            const float* __restrict__ btab, const int* __restrict__ ridx,
                            unsigned short* __restrict__ ws) {
  int t = blockIdx.x * blockDim.x + threadIdx.x;
  int nt = gridDim.x * blockDim.x;
  for (int i = t; i < 49152; i += nt) ws[i] = f2b(qkvw[i]);
  for (int i = t; i < 16384; i += nt) ws[49152 + i] = f2b(projw[i]);
  for (int i = t; i < 16384; i += nt) {
    int h = i >> 12, r = i & 4095, j = r >> 6, ii = r & 63;
    ws[65536 + i] = f2b(btab[ridx[ii * 64 + j] * 4 + h]);
  }
}

#define LOG2E 1.44269504088896340736f
#define QSCALE 0.17677669529663687f  // 32^-0.5

__global__ __launch_bounds__(256, 2)
void win_attn_kernel(const float* __restrict__ x, const float* __restrict__ mask,
                     const float* __restrict__ qkv_b, const float* __restrict__ proj_b,
                     const unsigned short* __restrict__ ws, float* __restrict__ out) {
  // LDS (shorts): [0,24576) per-head blocks of 6144: q[0,2048) k[2048,4096) vt[4096,6144)
  //               [24576,32768) xA [64][128] (later attn_out)
  //               [32768,36864) maskT [64 keys][64 rows]
  __shared__ short sm[36864];
  const int XA = 24576, MT = 32768;

  const int b = blockIdx.x;
  const int tid = threadIdx.x;
  const int wid = tid >> 6;   // wave id == head
  const int lane = tid & 63;
  const int l15 = lane & 15;
  const int g = lane >> 4;
  const int wm = b & 1023;

  // ---------------- phase 0: stage x (bf16, swizzled) + maskT ----------------
  {
    const float4* xw = (const float4*)(x + (size_t)b * 8192);
#pragma unroll
    for (int it = 0; it < 4; ++it) {
      int c = it * 256 + tid;           // 8-elem chunk 0..1023
      int row = c >> 4, ch = c & 15;
      float4 a0 = xw[c * 2], a1 = xw[c * 2 + 1];
      short8 v;
      v[0] = (short)f2b(a0.x); v[1] = (short)f2b(a0.y);
      v[2] = (short)f2b(a0.z); v[3] = (short)f2b(a0.w);
      v[4] = (short)f2b(a1.x); v[5] = (short)f2b(a1.y);
      v[6] = (short)f2b(a1.z); v[7] = (short)f2b(a1.w);
      *(short8*)&sm[XA + row * 128 + ((ch ^ (row & 7)) << 3)] = v;
    }
    const float4* mw = (const float4*)(mask + (size_t)wm * 4096);
#pragma unroll
    for (int it = 0; it < 4; ++it) {
      int fi = it * 256 + tid;          // float4 idx 0..1023
      int i = fi >> 4, j0 = (fi & 15) * 4;
      float4 m4 = mw[fi];
      int ic = i >> 2, ilo = i & 3;
      float mv[4] = {m4.x, m4.y, m4.z, m4.w};
#pragma unroll
      for (int e = 0; e < 4; ++e) {
        int j = j0 + e;
        sm[MT + j * 64 + ((ic ^ (j & 15)) << 2) + ilo] = (short)f2b(mv[e]);
      }
    }
  }
  __syncthreads();

  // ---------------- phase 1: QKV GEMM (wave computes its head's q,k,v) -------
  const int h = wid;
  const int qbase = h * 6144;
  float4v acc[4][6];
#pragma unroll
  for (int ri = 0; ri < 4; ++ri)
#pragma unroll
    for (int c = 0; c < 6; ++c) { acc[ri][c][0]=0.f; acc[ri][c][1]=0.f; acc[ri][c][2]=0.f; acc[ri][c][3]=0.f; }

#pragma unroll
  for (int kt = 0; kt < 4; ++kt) {
    short8 af[4];
#pragma unroll
    for (int ri = 0; ri < 4; ++ri) {
      int row = 16 * ri + l15;
      af[ri] = *(const short8*)&sm[XA + row * 128 + (((4 * kt + g) ^ (l15 & 7)) << 3)];
    }
#pragma unroll
    for (int mt = 0; mt < 3; ++mt) {
#pragma unroll
      for (int ct = 0; ct < 2; ++ct) {
        int col = mt * 128 + h * 32 + ct * 16 + l15;
        short8 bf = *(const short8*)&ws[col * 128 + kt * 32 + g * 8];
#pragma unroll
        for (int ri = 0; ri < 4; ++ri)
          acc[ri][mt * 2 + ct] =
              __builtin_amdgcn_mfma_f32_16x16x32_bf16(af[ri], bf, acc[ri][mt * 2 + ct], 0, 0, 0);
      }
    }
  }

  // epilogue: +bias, (scale q), convert, store q/k row-major [64][32], v transposed [32][64]
#pragma unroll
  for (int mt = 0; mt < 3; ++mt) {
#pragma unroll
    for (int ct = 0; ct < 2; ++ct) {
      int col = mt * 128 + h * 32 + ct * 16 + l15;
      float bias = qkv_b[col];
      int d = ct * 16 + l15;  // 0..31
#pragma unroll
      for (int ri = 0; ri < 4; ++ri) {
        float4v v = acc[ri][mt * 2 + ct];
        if (mt == 0) {
#pragma unroll
          for (int j = 0; j < 4; ++j) {
            int row = 16 * ri + 4 * g + j;
            float qv = (v[j] + bias) * QSCALE;
            sm[qbase + row * 32 + ((((d >> 3) ^ ((row >> 1) & 3))) << 3) + (d & 7)] = (short)f2b(qv);
          }
        } else if (mt == 1) {
#pragma unroll
          for (int j = 0; j < 4; ++j) {
            int row = 16 * ri + 4 * g + j;
            sm[qbase + 2048 + row * 32 + ((((d >> 3) ^ ((row >> 1) & 3))) << 3) + (d & 7)] = (short)f2b(v[j] + bias);
          }
        } else {
          short4v pv;
#pragma unroll
          for (int j = 0; j < 4; ++j) pv[j] = (short)f2b(v[j] + bias);
          int mc = 2 * ri + (g >> 1);
          *(short4v*)&sm[qbase + 4096 + d * 64 + ((mc ^ (d & 7)) << 3) + ((g & 1) << 2)] = pv;
        }
      }
    }
  }

  // ---------------- phase 2: S = qk^T, +bias+mask, softmax, PV ---------------
  short8 qa[4], kb[4];
#pragma unroll
  for (int ri = 0; ri < 4; ++ri) {
    int row = 16 * ri + l15;
    qa[ri] = *(const short8*)&sm[qbase + row * 32 + ((g ^ ((l15 >> 1) & 3)) << 3)];
  }
#pragma unroll
  for (int ci = 0; ci < 4; ++ci) {
    int row = 16 * ci + l15;
    kb[ci] = *(const short8*)&sm[qbase + 2048 + row * 32 + ((g ^ ((l15 >> 1) & 3)) << 3)];
  }
  float4v s[4][4];
#pragma unroll
  for (int ri = 0; ri < 4; ++ri)
#pragma unroll
    for (int ci = 0; ci < 4; ++ci) {
      float4v z; z[0]=0.f; z[1]=0.f; z[2]=0.f; z[3]=0.f;
      s[ri][ci] = __builtin_amdgcn_mfma_f32_16x16x32_bf16(qa[ri], kb[ci], z, 0, 0, 0);
    }

  // add relative-position bias (biasT global, bf16) + window mask (maskT LDS, bf16)
  const unsigned short* bt = ws + 65536 + h * 4096;
#pragma unroll
  for (int ri = 0; ri < 4; ++ri) {
    int i0 = 16 * ri + 4 * g;
    int ic = i0 >> 2;  // 4ri+g
#pragma unroll
    for (int ci = 0; ci < 4; ++ci) {
      int key = 16 * ci + l15;
      short4v mv = *(const short4v*)&sm[MT + key * 64 + ((ic ^ (key & 15)) << 2)];
      short4v bv = *(const short4v*)&bt[key * 64 + i0];
#pragma unroll
      for (int j = 0; j < 4; ++j)
        s[ri][ci][j] += b2f((unsigned short)mv[j]) + b2f((unsigned short)bv[j]);
    }
  }

  // row softmax: row r = 16ri+4g+j lives in lanes sharing g (shuffle width 16 over cols)
#pragma unroll
  for (int ri = 0; ri < 4; ++ri) {
#pragma unroll
    for (int j = 0; j < 4; ++j) {
      float m = fmaxf(fmaxf(s[ri][0][j], s[ri][1][j]), fmaxf(s[ri][2][j], s[ri][3][j]));
#pragma unroll
      for (int dl = 1; dl < 16; dl <<= 1) m = fmaxf(m, __shfl_xor(m, dl, 16));
      float sum = 0.f;
#pragma unroll
      for (int ci = 0; ci < 4; ++ci) {
        float p = exp2f((s[ri][ci][j] - m) * LOG2E);
        s[ri][ci][j] = p;
        sum += p;
      }
#pragma unroll
      for (int dl = 1; dl < 16; dl <<= 1) sum += __shfl_xor(sum, dl, 16);
      float rs = __builtin_amdgcn_rcpf(sum);
#pragma unroll
      for (int ci = 0; ci < 4; ++ci) s[ri][ci][j] *= rs;
    }
  }

  // write P: keys 0-31 over q region, keys 32-63 over k region (both dead)
#pragma unroll
  for (int ci = 0; ci < 4; ++ci) {
    int rbase = qbase + ((ci >= 2) ? 2048 : 0);
    int kk = (16 * ci + l15) & 31;
#pragma unroll
    for (int ri = 0; ri < 4; ++ri) {
#pragma unroll
      for (int j = 0; j < 4; ++j) {
        int row = 16 * ri + 4 * g + j;
        sm[rbase + row * 32 + ((((kk >> 3) ^ ((row >> 1) & 3))) << 3) + (kk & 7)] = (short)f2b(s[ri][ci][j]);
      }
    }
  }

  // PV: out_h[64][32]
  float4v oacc[4][2];
#pragma unroll
  for (int ri = 0; ri < 4; ++ri)
#pragma unroll
    for (int ct = 0; ct < 2; ++ct) { oacc[ri][ct][0]=0.f; oacc[ri][ct][1]=0.f; oacc[ri][ct][2]=0.f; oacc[ri][ct][3]=0.f; }
#pragma unroll
  for (int half = 0; half < 2; ++half) {
    int aBase = qbase + (half ? 2048 : 0);
    short8 pa[4];
#pragma unroll
    for (int ri = 0; ri < 4; ++ri) {
      int row = 16 * ri + l15;
      pa[ri] = *(const short8*)&sm[aBase + row * 32 + ((g ^ ((l15 >> 1) & 3)) << 3)];
    }
#pragma unroll
    for (int ct = 0; ct < 2; ++ct) {
      int d = 16 * ct + l15;
      short8 vb = *(const short8*)&sm[qbase + 4096 + d * 64 + (((4 * half + g) ^ (d & 7)) << 3)];
#pragma unroll
      for (int ri = 0; ri < 4; ++ri)
        oacc[ri][ct] = __builtin_amdgcn_mfma_f32_16x16x32_bf16(pa[ri], vb, oacc[ri][ct], 0, 0, 0);
    }
  }

  __syncthreads();  // all waves done reading xA region
  // write attn_out bf16 into xA region [64][128]
#pragma unroll
  for (int ct = 0; ct < 2; ++ct) {
    int col = 32 * h + 16 * ct + l15;
    int ch = col >> 3;
#pragma unroll
    for (int ri = 0; ri < 4; ++ri) {
#pragma unroll
      for (int j = 0; j < 4; ++j) {
        int row = 16 * ri + 4 * g + j;
        sm[XA + row * 128 + ((ch ^ (row & 7)) << 3) + (col & 7)] = (short)f2b(oacc[ri][ct][j]);
      }
    }
  }
  __syncthreads();

  // ---------------- phase 3: output projection -------------------------------
  float4v po[4][2];
#pragma unroll
  for (int ri = 0; ri < 4; ++ri)
#pragma unroll
    for (int ct = 0; ct < 2; ++ct) { po[ri][ct][0]=0.f; po[ri][ct][1]=0.f; po[ri][ct][2]=0.f; po[ri][ct][3]=0.f; }
#pragma unroll
  for (int kt = 0; kt < 4; ++kt) {
    short8 af[4];
#pragma unroll
    for (int ri = 0; ri < 4; ++ri) {
      int row = 16 * ri + l15;
      af[ri] = *(const short8*)&sm[XA + row * 128 + (((4 * kt + g) ^ (l15 & 7)) << 3)];
    }
#pragma unroll
    for (int ct = 0; ct < 2; ++ct) {
      int col = 32 * wid + ct * 16 + l15;
      short8 bf = *(const short8*)&ws[49152 + col * 128 + kt * 32 + g * 8];
#pragma unroll
      for (int ri = 0; ri < 4; ++ri)
        po[ri][ct] = __builtin_amdgcn_mfma_f32_16x16x32_bf16(af[ri], bf, po[ri][ct], 0, 0, 0);
    }
  }
  float* ob = out + (size_t)b * 8192;
#pragma unroll
  for (int ct = 0; ct < 2; ++ct) {
    int col = 32 * wid + ct * 16 + l15;
    float pb = proj_b[col];
#pragma unroll
    for (int ri = 0; ri < 4; ++ri) {
#pragma unroll
      for (int j = 0; j < 4; ++j) {
        int row = 16 * ri + 4 * g + j;
        ob[row * 128 + col] = po[ri][ct][j] + pb;
      }
    }
  }
}

extern "C" void kernel_launch(void* const* d_in, const int* in_sizes, int n_in,
                              void* d_out, int out_size, void* d_ws, size_t ws_size,
                              hipStream_t stream) {
  const float* x      = (const float*)d_in[0];
  const float* mask   = (const float*)d_in[1];
  const float* qkv_w  = (const float*)d_in[2];
  const float* qkv_b  = (const float*)d_in[3];
  const float* proj_w = (const float*)d_in[4];
  const float* proj_b = (const float*)d_in[5];
  const float* btab   = (const float*)d_in[6];
  const int*   ridx   = (const int*)d_in[7];
  unsigned short* ws  = (unsigned short*)d_ws;
  float* out = (float*)d_out;

  hipLaunchKernelGGL(prep_kernel, dim3(64), dim3(256), 0, stream, qkv_w, proj_w, btab, ridx, ws);
  hipLaunchKernelGGL(win_attn_kernel, dim3(8192), dim3(256), 0, stream,
                     x, mask, qkv_b, proj_b, ws, out);
}

// Round 2
// 287.834 us; speedup vs baseline: 1.0688x; 1.0688x over previous
//
#include <hip/hip_runtime.h>

typedef __attribute__((ext_vector_type(8))) short short8;
typedef __attribute__((ext_vector_type(4))) short short4v;
typedef __attribute__((ext_vector_type(4))) float float4v;

#define DEV static __device__ __forceinline__

DEV float b2f(unsigned short u) { return __uint_as_float(((unsigned)u) << 16); }
DEV unsigned short f2b(float f) {
  return __builtin_bit_cast(unsigned short, static_cast<__bf16>(f));
}

// ws layout (2-byte units):
// [0, 49152)      qkv_w bf16  [384][128]   (out_col, k) k-contiguous
// [49152, 65536)  proj_w bf16 [128][128]
// [65536, 81920)  biasM bf16  [4][64 q-row][64 key]  row-major
__global__ void prep_kernel(const float* __restrict__ qkvw, const float* __restrict__ projw,
                            const float* __restrict__ btab, const int* __restrict__ ridx,
                            unsigned short* __restrict__ ws) {
  int t = blockIdx.x * blockDim.x + threadIdx.x;
  int nt = gridDim.x * blockDim.x;
  for (int i = t; i < 49152; i += nt) ws[i] = f2b(qkvw[i]);
  for (int i = t; i < 16384; i += nt) ws[49152 + i] = f2b(projw[i]);
  for (int i = t; i < 16384; i += nt) {
    int h = i >> 12, r = i & 4095;
    ws[65536 + i] = f2b(btab[ridx[r] * 4 + h]);
  }
}

#define LOG2E 1.44269504088896340736f
#define QSCALE 0.17677669529663687f  // 32^-0.5

__global__ __launch_bounds__(256, 2)
void win_attn_kernel(const float* __restrict__ x, const float* __restrict__ mask,
                     const float* __restrict__ qkv_b, const float* __restrict__ proj_b,
                     const unsigned short* __restrict__ ws, float* __restrict__ out) {
  // LDS shorts: [0,8192) xA [64][128] swizzled (later attn_out)
  //             [8192 + h*6144): q[64][32], k[64][32], vt[32][64]; P[64][64] overlays q+k
  //             [32768,36864) maskM [64 row][64 key] swizzled
  __shared__ short sm[36864];
  const int HB = 8192, MT = 32768;

  const int b = blockIdx.x;
  const int tid = threadIdx.x;
  const int h = tid >> 6;       // wave id == head
  const int lane = tid & 63;
  const int l15 = lane & 15;
  const int g = lane >> 4;
  const int g1 = g & 1, g2 = g >> 1;
  const int wm = b & 1023;

  // ---------------- phase 0: stage x + mask (both bf16, swizzled) ------------
  {
    const float4* xw = (const float4*)(x + (size_t)b * 8192);
#pragma unroll
    for (int it = 0; it < 4; ++it) {
      int c = it * 256 + tid;           // 8-elem chunk 0..1023
      int row = c >> 4, ch = c & 15;
      float4 a0 = xw[c * 2], a1 = xw[c * 2 + 1];
      short8 v;
      v[0] = (short)f2b(a0.x); v[1] = (short)f2b(a0.y);
      v[2] = (short)f2b(a0.z); v[3] = (short)f2b(a0.w);
      v[4] = (short)f2b(a1.x); v[5] = (short)f2b(a1.y);
      v[6] = (short)f2b(a1.z); v[7] = (short)f2b(a1.w);
      *(short8*)&sm[row * 128 + ((ch ^ (row & 7)) << 3)] = v;
    }
    const float4* mw = (const float4*)(mask + (size_t)wm * 4096);
#pragma unroll
    for (int it = 0; it < 4; ++it) {
      int fi = it * 256 + tid;          // float4 idx 0..1023
      int i = fi >> 4, j0 = (fi & 15) << 2;
      float4 m4 = mw[fi];
      short4v v;
      v[0] = (short)f2b(m4.x); v[1] = (short)f2b(m4.y);
      v[2] = (short)f2b(m4.z); v[3] = (short)f2b(m4.w);
      *(short4v*)&sm[MT + i * 64 + (((j0 >> 3) ^ (i & 7)) << 3) + (j0 & 7)] = v;
    }
  }
  __syncthreads();

  // ---------------- phase 1: QKV GEMM ----------------------------------------
  const int Hb = HB + h * 6144;
  float4v aq[2][2][4];  // [mt(q/k)][oc][ri]  (swapped: rows=outcol, cols=token)
  float4v av[2][4];     // [oc][ri]           (unswapped: rows=token, cols=d)
#pragma unroll
  for (int mt = 0; mt < 2; ++mt)
#pragma unroll
    for (int oc = 0; oc < 2; ++oc)
#pragma unroll
      for (int ri = 0; ri < 4; ++ri) {
        aq[mt][oc][ri][0]=0.f; aq[mt][oc][ri][1]=0.f; aq[mt][oc][ri][2]=0.f; aq[mt][oc][ri][3]=0.f;
      }
#pragma unroll
  for (int oc = 0; oc < 2; ++oc)
#pragma unroll
    for (int ri = 0; ri < 4; ++ri) {
      av[oc][ri][0]=0.f; av[oc][ri][1]=0.f; av[oc][ri][2]=0.f; av[oc][ri][3]=0.f;
    }

#pragma unroll
  for (int kt = 0; kt < 4; ++kt) {
    short8 af[4];
#pragma unroll
    for (int ri = 0; ri < 4; ++ri) {
      int row = 16 * ri + l15;
      af[ri] = *(const short8*)&sm[row * 128 + (((4 * kt + g) ^ (row & 7)) << 3)];
    }
    short8 wqk[2][2], wv[2];
#pragma unroll
    for (int mt = 0; mt < 2; ++mt)
#pragma unroll
      for (int oc = 0; oc < 2; ++oc)
        wqk[mt][oc] = *(const short8*)&ws[(mt * 128 + h * 32 + oc * 16 + l15) * 128 + kt * 32 + g * 8];
#pragma unroll
    for (int oc = 0; oc < 2; ++oc)
      wv[oc] = *(const short8*)&ws[(256 + h * 32 + oc * 16 + l15) * 128 + kt * 32 + g * 8];
#pragma unroll
    for (int mt = 0; mt < 2; ++mt)
#pragma unroll
      for (int oc = 0; oc < 2; ++oc)
#pragma unroll
        for (int ri = 0; ri < 4; ++ri)
          aq[mt][oc][ri] = __builtin_amdgcn_mfma_f32_16x16x32_bf16(wqk[mt][oc], af[ri], aq[mt][oc][ri], 0, 0, 0);
#pragma unroll
    for (int oc = 0; oc < 2; ++oc)
#pragma unroll
      for (int ri = 0; ri < 4; ++ri)
        av[oc][ri] = __builtin_amdgcn_mfma_f32_16x16x32_bf16(af[ri], wv[oc], av[oc][ri], 0, 0, 0);
  }

  // epilogue q/k: lane owns row 16ri+l15, cols 16oc+4g+{0..3} -> 8B stores
#pragma unroll
  for (int mt = 0; mt < 2; ++mt)
#pragma unroll
    for (int oc = 0; oc < 2; ++oc) {
      float4v bb = *(const float4v*)&qkv_b[mt * 128 + h * 32 + oc * 16 + 4 * g];
      int chs = 2 * oc + g2;
#pragma unroll
      for (int ri = 0; ri < 4; ++ri) {
        int row = 16 * ri + l15;
        short4v pv;
#pragma unroll
        for (int j = 0; j < 4; ++j) {
          float vv = aq[mt][oc][ri][j] + bb[j];
          if (mt == 0) vv *= QSCALE;
          pv[j] = (short)f2b(vv);
        }
        *(short4v*)&sm[Hb + mt * 2048 + row * 32 + ((chs ^ ((row >> 1) & 3)) << 3) + 4 * g1] = pv;
      }
    }
  // epilogue v: lane owns col d=16oc+l15, keys 16ri+4g+{0..3} -> 8B stores to vt[d][key]
#pragma unroll
  for (int oc = 0; oc < 2; ++oc) {
    float bv = qkv_b[256 + h * 32 + oc * 16 + l15];
    int d = oc * 16 + l15;
#pragma unroll
    for (int ri = 0; ri < 4; ++ri) {
      short4v pv;
#pragma unroll
      for (int j = 0; j < 4; ++j) pv[j] = (short)f2b(av[oc][ri][j] + bv);
      *(short4v*)&sm[Hb + 4096 + d * 64 + (((2 * ri + g2) ^ (d & 7)) << 3) + 4 * g1] = pv;
    }
  }

  // ---------------- phase 2: S^T = mfma(k,q) with C=bias+mask ----------------
  short8 qa[4], ka[4];
#pragma unroll
  for (int ri = 0; ri < 4; ++ri) {
    int row = 16 * ri + l15;
    qa[ri] = *(const short8*)&sm[Hb + row * 32 + ((g ^ ((row >> 1) & 3)) << 3)];
  }
#pragma unroll
  for (int ci = 0; ci < 4; ++ci) {
    int row = 16 * ci + l15;
    ka[ci] = *(const short8*)&sm[Hb + 2048 + row * 32 + ((g ^ ((row >> 1) & 3)) << 3)];
  }
  const unsigned short* bt = ws + 65536 + h * 4096;
  float4v st[4][4];  // lane holds S[q=16ri+l15][key=16ci+4g+j]
#pragma unroll
  for (int ri = 0; ri < 4; ++ri) {
    int row = 16 * ri + l15;
#pragma unroll
    for (int ci = 0; ci < 4; ++ci) {
      short4v mv = *(const short4v*)&sm[MT + row * 64 + (((2 * ci + g2) ^ (row & 7)) << 3) + 4 * g1];
      short4v bv = *(const short4v*)&bt[row * 64 + ci * 16 + 4 * g];
      float4v c;
#pragma unroll
      for (int j = 0; j < 4; ++j) c[j] = b2f((unsigned short)mv[j]) + b2f((unsigned short)bv[j]);
      st[ri][ci] = __builtin_amdgcn_mfma_f32_16x16x32_bf16(ka[ci], qa[ri], c, 0, 0, 0);
    }
  }

  // softmax over keys: per-lane 16 partials + 2 shuffles (reduce over g)
#pragma unroll
  for (int ri = 0; ri < 4; ++ri) {
    float m = st[ri][0][0];
#pragma unroll
    for (int ci = 0; ci < 4; ++ci)
#pragma unroll
      for (int j = 0; j < 4; ++j) m = fmaxf(m, st[ri][ci][j]);
    m = fmaxf(m, __shfl_xor(m, 16));
    m = fmaxf(m, __shfl_xor(m, 32));
    float mL = m * LOG2E;
    float sum = 0.f;
#pragma unroll
    for (int ci = 0; ci < 4; ++ci)
#pragma unroll
      for (int j = 0; j < 4; ++j) {
        float p = exp2f(__builtin_fmaf(st[ri][ci][j], LOG2E, -mL));
        st[ri][ci][j] = p;
        sum += p;
      }
    sum += __shfl_xor(sum, 16);
    sum += __shfl_xor(sum, 32);
    float rs = __builtin_amdgcn_rcpf(sum);
    int row = 16 * ri + l15;
#pragma unroll
    for (int ci = 0; ci < 4; ++ci) {
      short4v pv;
#pragma unroll
      for (int j = 0; j < 4; ++j) pv[j] = (short)f2b(st[ri][ci][j] * rs);
      *(short4v*)&sm[Hb + row * 64 + (((2 * ci + g2) ^ (row & 7)) << 3) + 4 * g1] = pv;
    }
  }

  // ---------------- PV: out^T = mfma(vt, P) ----------------------------------
  short8 va[2][2], pbf[4][2];
#pragma unroll
  for (int dt = 0; dt < 2; ++dt)
#pragma unroll
    for (int hf = 0; hf < 2; ++hf) {
      int dr = 16 * dt + l15;
      va[dt][hf] = *(const short8*)&sm[Hb + 4096 + dr * 64 + (((4 * hf + g) ^ (dr & 7)) << 3)];
    }
#pragma unroll
  for (int ri = 0; ri < 4; ++ri)
#pragma unroll
    for (int hf = 0; hf < 2; ++hf) {
      int row = 16 * ri + l15;
      pbf[ri][hf] = *(const short8*)&sm[Hb + row * 64 + (((4 * hf + g) ^ (row & 7)) << 3)];
    }
  float4v ot[2][4];
#pragma unroll
  for (int dt = 0; dt < 2; ++dt)
#pragma unroll
    for (int ri = 0; ri < 4; ++ri) { ot[dt][ri][0]=0.f; ot[dt][ri][1]=0.f; ot[dt][ri][2]=0.f; ot[dt][ri][3]=0.f; }
#pragma unroll
  for (int hf = 0; hf < 2; ++hf)
#pragma unroll
    for (int dt = 0; dt < 2; ++dt)
#pragma unroll
      for (int ri = 0; ri < 4; ++ri)
        ot[dt][ri] = __builtin_amdgcn_mfma_f32_16x16x32_bf16(va[dt][hf], pbf[ri][hf], ot[dt][ri], 0, 0, 0);

  __syncthreads();  // all waves done with xA reads (phase 1 finished)
  // attn_out: lane owns row 16ri+l15, cols 32h+16dt+4g+{0..3} -> 8B stores
#pragma unroll
  for (int dt = 0; dt < 2; ++dt) {
    int ch = 4 * h + 2 * dt + g2;
#pragma unroll
    for (int ri = 0; ri < 4; ++ri) {
      int row = 16 * ri + l15;
      short4v pv;
#pragma unroll
      for (int j = 0; j < 4; ++j) pv[j] = (short)f2b(ot[dt][ri][j]);
      *(short4v*)&sm[row * 128 + ((ch ^ (row & 7)) << 3) + 4 * g1] = pv;
    }
  }
  __syncthreads();

  // ---------------- phase 3: out^T = mfma(projW, attn_out) -------------------
  float4v po[2][4];
#pragma unroll
  for (int oc = 0; oc < 2; ++oc)
#pragma unroll
    for (int ri = 0; ri < 4; ++ri) { po[oc][ri][0]=0.f; po[oc][ri][1]=0.f; po[oc][ri][2]=0.f; po[oc][ri][3]=0.f; }
#pragma unroll
  for (int kt = 0; kt < 4; ++kt) {
    short8 af[4];
#pragma unroll
    for (int ri = 0; ri < 4; ++ri) {
      int row = 16 * ri + l15;
      af[ri] = *(const short8*)&sm[row * 128 + (((4 * kt + g) ^ (row & 7)) << 3)];
    }
    short8 pw[2];
#pragma unroll
    for (int oc = 0; oc < 2; ++oc)
      pw[oc] = *(const short8*)&ws[49152 + (h * 32 + oc * 16 + l15) * 128 + kt * 32 + g * 8];
#pragma unroll
    for (int oc = 0; oc < 2; ++oc)
#pragma unroll
      for (int ri = 0; ri < 4; ++ri)
        po[oc][ri] = __builtin_amdgcn_mfma_f32_16x16x32_bf16(pw[oc], af[ri], po[oc][ri], 0, 0, 0);
  }
  float* ob = out + (size_t)b * 8192;
#pragma unroll
  for (int oc = 0; oc < 2; ++oc) {
    float4v pb4 = *(const float4v*)&proj_b[h * 32 + oc * 16 + 4 * g];
#pragma unroll
    for (int ri = 0; ri < 4; ++ri) {
      int row = 16 * ri + l15;
      float4 o = make_float4(po[oc][ri][0] + pb4[0], po[oc][ri][1] + pb4[1],
                             po[oc][ri][2] + pb4[2], po[oc][ri][3] + pb4[3]);
      *(float4*)&ob[row * 128 + h * 32 + oc * 16 + 4 * g] = o;
    }
  }
}

extern "C" void kernel_launch(void* const* d_in, const int* in_sizes, int n_in,
                              void* d_out, int out_size, void* d_ws, size_t ws_size,
                              hipStream_t stream) {
  const float* x      = (const float*)d_in[0];
  const float* mask   = (const float*)d_in[1];
  const float* qkv_w  = (const float*)d_in[2];
  const float* qkv_b  = (const float*)d_in[3];
  const float* proj_w = (const float*)d_in[4];
  const float* proj_b = (const float*)d_in[5];
  const float* btab   = (const float*)d_in[6];
  const int*   ridx   = (const int*)d_in[7];
  unsigned short* ws  = (unsigned short*)d_ws;
  float* out = (float*)d_out;

  hipLaunchKernelGGL(prep_kernel, dim3(64), dim3(256), 0, stream, qkv_w, proj_w, btab, ridx, ws);
  hipLaunchKernelGGL(win_attn_kernel, dim3(8192), dim3(256), 0, stream,
                     x, mask, qkv_b, proj_b, ws, out);
}